// Round 7
// baseline (832.648 us; speedup 1.0000x reference)
//
#include <hip/hip_runtime.h>

#define HD 1024
#define BB 64
#define II 512

typedef float f4 __attribute__((ext_vector_type(4)));

__device__ __forceinline__ float fast_tanh(float x) {
    float ax = __builtin_fabsf(x);
    float e  = __builtin_amdgcn_exp2f(ax * -2.8853900817779268f);  // exp(-2|x|)
    float t  = (1.0f - e) * __builtin_amdgcn_rcpf(1.0f + e);
    return x < 0.0f ? -t : t;
}

// out[b][h] = tanh( sum_k A[b][k] * W[h][k] + bias[h] )
// Block = 1024 thr = 16 waves = 16 b's sharing one h-octet whose 8 W rows
// are staged in LDS once. grid 512 = 128 octets x 4 b-groups.
// First gemm also zeroes the sync counters (block 0).
template <int K>
__global__ __launch_bounds__(1024) void k_gemm(const float* __restrict__ A,    // [64][K]
                                               const float* __restrict__ W,    // [1024][K]
                                               const float* __restrict__ bias, // [1024]
                                               float* __restrict__ out,        // [64][1024]
                                               int* __restrict__ syncb)
{
    constexpr int J = K / 256;
    __shared__ float wlds[8 * K];

    int tid  = threadIdx.x;
    if (syncb && blockIdx.x == 0 && tid < 192) syncb[tid] = 0;

    int oct  = blockIdx.x & 127;
    int bg   = blockIdx.x >> 7;          // 0..3
    int h0   = oct * 8;

    {
        const f4* src = (const f4*)(W + (size_t)h0 * K);
        f4* dst = (f4*)wlds;
#pragma unroll
        for (int v = tid; v < 2 * K; v += 1024) dst[v] = src[v];
    }
    __syncthreads();

    int lane = tid & 63;
    int wave = tid >> 6;
    int b    = bg * 16 + wave;

    f4 a[J];
#pragma unroll
    for (int j = 0; j < J; ++j)
        a[j] = *(const f4*)(A + (size_t)b * K + j * 256 + lane * 4);

    float acc[8];
#pragma unroll
    for (int hh = 0; hh < 8; ++hh) {
        const float* wrow = wlds + hh * K;
        float s = 0.f;
#pragma unroll
        for (int j = 0; j < J; ++j) {
            f4 w4 = *(const f4*)(wrow + j * 256 + lane * 4);
            s += a[j].x * w4.x + a[j].y * w4.y + a[j].z * w4.z + a[j].w * w4.w;
        }
        acc[hh] = s;
    }
#pragma unroll
    for (int hh = 0; hh < 8; ++hh)
#pragma unroll
        for (int off = 32; off; off >>= 1)
            acc[hh] += __shfl_xor(acc[hh], off, 64);
    if (lane == 0) {
        f4 o0, o1;
        o0.x = fast_tanh(acc[0] + bias[h0 + 0]);
        o0.y = fast_tanh(acc[1] + bias[h0 + 1]);
        o0.z = fast_tanh(acc[2] + bias[h0 + 2]);
        o0.w = fast_tanh(acc[3] + bias[h0 + 3]);
        o1.x = fast_tanh(acc[4] + bias[h0 + 4]);
        o1.y = fast_tanh(acc[5] + bias[h0 + 5]);
        o1.z = fast_tanh(acc[6] + bias[h0 + 6]);
        o1.w = fast_tanh(acc[7] + bias[h0 + 7]);
        *(f4*)(out + (size_t)b * HD + h0)     = o0;
        *(f4*)(out + (size_t)b * HD + h0 + 4) = o1;
    }
}

// Persistent fused kernel: 1024 blocks x 512 thr (4 blocks/CU, 8 waves/SIMD).
// 16 blocks per b ("group"); block owns h-slice [sub*64, sub*64+64).
// Phase 1: plastic+fc2 -> pre/hidden (pw first read, allocating).
// Phase 2: hrc rows for slice + nm/choice/value partials; sub0 finalizes nm[b].
// Phase 3: update for slice (pw re-read a few us later -> L2/L3 hit), NT stores.
__global__ __launch_bounds__(512, 8) void k_fused(
        const float* __restrict__ pw,
        const float* __restrict__ alpha,
        const float* __restrict__ Wfc2,
        const float* __restrict__ bfc2,
        const float* __restrict__ x2,      // [64][1024]
        const float* __restrict__ reward,  // [64]
        const float* __restrict__ Wr,      // [1024]
        const float* __restrict__ br,      // [1024]
        const float* __restrict__ Whr,
        const float* __restrict__ bhr,
        const float* __restrict__ Wnm,
        const float* __restrict__ bnm,
        const float* __restrict__ Wch,
        const float* __restrict__ bch,
        const float* __restrict__ Wv,
        const float* __restrict__ bv,
        float* __restrict__ out_choice,
        float* __restrict__ out_nm,
        float* __restrict__ out_value,
        float* __restrict__ out_newpw,
        float* __restrict__ out_hidden,
        float* __restrict__ parts,         // [64][16][4]
        int*   __restrict__ cnt_p,         // [64]
        int*   __restrict__ cnt_h,         // [64]
        int*   __restrict__ flag_nm)       // [64]
{
    __shared__ float xs[HD];
    __shared__ float pre_s[64];
    __shared__ float hid_s[64];
    __shared__ float hplus[HD];
    __shared__ float wred[8][4];
    __shared__ float nm_lds;

    int tid   = threadIdx.x;
    int lane  = tid & 63;
    int wave  = tid >> 6;          // 0..7
    int b     = blockIdx.x >> 4;
    int sub   = blockIdx.x & 15;
    int hbase = sub << 6;

    if (tid < 256) ((f4*)xs)[tid] = ((const f4*)(x2 + ((size_t)b << 10)))[tid];
    __syncthreads();

    // ---- Phase 1: plastic + innate for 64-h slice (8 rows per wave) ----
    for (int rr = 0; rr < 8; ++rr) {
        int hl = (wave << 3) + rr;
        int h  = hbase + hl;
        const float* prow = pw + ((size_t)b << 20) + ((size_t)h << 10);
        const float* ar   = alpha + ((size_t)h << 10);
        const float* wr   = Wfc2 + ((size_t)h << 10);
        float accp = 0.f, acci = 0.f;
#pragma unroll
        for (int j = 0; j < 4; ++j) {
            int i = j * 256 + lane * 4;
            f4 p4 = *(const f4*)(prow + i);
            f4 a4 = *(const f4*)(ar + i);
            f4 w4 = *(const f4*)(wr + i);
            f4 x4 = *(const f4*)(xs + i);
            accp += a4.x * p4.x * x4.x + a4.y * p4.y * x4.y +
                    a4.z * p4.z * x4.z + a4.w * p4.w * x4.w;
            acci += w4.x * x4.x + w4.y * x4.y + w4.z * x4.z + w4.w * x4.w;
        }
#pragma unroll
        for (int off = 32; off; off >>= 1) {
            accp += __shfl_xor(accp, off, 64);
            acci += __shfl_xor(acci, off, 64);
        }
        if (lane == 0) {
            float pv = acci + bfc2[h] + accp;
            float hv = fast_tanh(pv);
            pre_s[hl] = pv;
            hid_s[hl] = hv;
            out_hidden[(b << 10) + h] = hv;
        }
    }
    __syncthreads();
    if (tid == 0) {
        __threadfence();
        __hip_atomic_fetch_add(&cnt_p[b], 1, __ATOMIC_ACQ_REL, __HIP_MEMORY_SCOPE_AGENT);
        while (__hip_atomic_load(&cnt_p[b], __ATOMIC_ACQUIRE, __HIP_MEMORY_SCOPE_AGENT) < 16)
            __builtin_amdgcn_s_sleep(1);
    }
    __syncthreads();
    __threadfence();   // all-thread acquire before reading cross-block out_hidden

    // ---- Phase 2: hrc rows for slice + partial dots ----
    float rwd = reward[b];
    for (int t = tid; t < HD; t += 512)
        hplus[t] = out_hidden[(b << 10) + t] + rwd * Wr[t] + br[t];
    __syncthreads();

    float nm0 = 0.f, nm1 = 0.f;
    for (int rr = 0; rr < 8; ++rr) {
        int h2 = hbase + (wave << 3) + rr;
        const float* wrow = Whr + ((size_t)h2 << 10);
        float s = 0.f;
#pragma unroll
        for (int j = 0; j < 4; ++j) {
            int i = j * 256 + lane * 4;
            f4 w4 = *(const f4*)(wrow + i);
            f4 h4 = *(const f4*)(hplus + i);
            s += w4.x * h4.x + w4.y * h4.y + w4.z * h4.z + w4.w * h4.w;
        }
#pragma unroll
        for (int off = 32; off; off >>= 1) s += __shfl_xor(s, off, 64);
        float hrcv = fast_tanh(s + bhr[h2]);
        if (lane == 0) {
            nm0 += Wnm[h2] * hrcv;
            nm1 += Wnm[HD + h2] * hrcv;
        }
    }
    float cv = 0.f, vv = 0.f;
    if (wave == 0) {
        cv = Wch[hbase + lane] * hid_s[lane];
        vv = Wv[hbase + lane] * hid_s[lane];
#pragma unroll
        for (int off = 32; off; off >>= 1) {
            cv += __shfl_xor(cv, off, 64);
            vv += __shfl_xor(vv, off, 64);
        }
    }
    if (lane == 0) {
        wred[wave][0] = nm0; wred[wave][1] = nm1;
        wred[wave][2] = cv;  wred[wave][3] = vv;    // waves>0 contribute 0
    }
    __syncthreads();
    if (tid == 0) {
        float p0 = 0.f, p1 = 0.f, p2 = 0.f, p3 = 0.f;
        for (int w = 0; w < 8; ++w) {
            p0 += wred[w][0]; p1 += wred[w][1];
            p2 += wred[w][2]; p3 += wred[w][3];
        }
        float* pb = parts + b * 64 + sub * 4;
        pb[0] = p0; pb[1] = p1; pb[2] = p2; pb[3] = p3;
        __threadfence();
        __hip_atomic_fetch_add(&cnt_h[b], 1, __ATOMIC_ACQ_REL, __HIP_MEMORY_SCOPE_AGENT);
        if (sub == 0) {
            while (__hip_atomic_load(&cnt_h[b], __ATOMIC_ACQUIRE, __HIP_MEMORY_SCOPE_AGENT) < 16)
                __builtin_amdgcn_s_sleep(1);
            __threadfence();
            float s0 = 0.f, s1 = 0.f, s2 = 0.f, s3 = 0.f;
            for (int q = 0; q < 16; ++q) {         // fixed order -> deterministic
                const float* pp = parts + b * 64 + q * 4;
                s0 += pp[0]; s1 += pp[1]; s2 += pp[2]; s3 += pp[3];
            }
            float n0 = fast_tanh(s0 + bnm[0]);
            float n1 = fast_tanh(s1 + bnm[1]);
            float nv = n0 - n1;
            out_nm[b] = nv;
            float z = s2 + bch[0];
            out_choice[b] = __builtin_amdgcn_rcpf(1.0f + __builtin_amdgcn_exp2f(-z * 1.4426950408889634f));
            out_value[b]  = s3 + bv[0];
            __threadfence();
            __hip_atomic_store(&flag_nm[b], 1, __ATOMIC_RELEASE, __HIP_MEMORY_SCOPE_AGENT);
        }
        while (__hip_atomic_load(&flag_nm[b], __ATOMIC_ACQUIRE, __HIP_MEMORY_SCOPE_AGENT) == 0)
            __builtin_amdgcn_s_sleep(1);
        nm_lds = out_nm[b];
    }
    __syncthreads();
    float nb = nm_lds;

    // ---- Phase 3: update for the same h-slice (pw still in L2/L3) ----
    for (int rr = 0; rr < 8; ++rr) {
        int hl = (wave << 3) + rr;
        int h  = hbase + hl;
        float ps = pre_s[hl];
        size_t base = ((size_t)b << 20) + ((size_t)h << 10);
#pragma unroll
        for (int j = 0; j < 4; ++j) {
            int i = j * 256 + lane * 4;
            f4 p4 = *(const f4*)(pw + base + i);
            f4 x4 = *(const f4*)(xs + i);
            f4 o4;
            o4.x = fminf(fmaxf(p4.x + nb * fast_tanh(ps * x4.x), -50.f), 50.f);
            o4.y = fminf(fmaxf(p4.y + nb * fast_tanh(ps * x4.y), -50.f), 50.f);
            o4.z = fminf(fmaxf(p4.z + nb * fast_tanh(ps * x4.z), -50.f), 50.f);
            o4.w = fminf(fmaxf(p4.w + nb * fast_tanh(ps * x4.w), -50.f), 50.f);
            __builtin_nontemporal_store(o4, (f4*)(out_newpw + base + i));
        }
    }
}

extern "C" void kernel_launch(void* const* d_in, const int* in_sizes, int n_in,
                              void* d_out, int out_size, void* d_ws, size_t ws_size,
                              hipStream_t stream) {
    const float* items  = (const float*)d_in[0];
    const float* pw     = (const float*)d_in[1];
    const float* reward = (const float*)d_in[2];
    const float* We     = (const float*)d_in[3];
    const float* be     = (const float*)d_in[4];
    const float* W1     = (const float*)d_in[5];
    const float* b1     = (const float*)d_in[6];
    const float* W2     = (const float*)d_in[7];
    const float* b2     = (const float*)d_in[8];
    const float* Wfc2   = (const float*)d_in[9];
    const float* bfc2   = (const float*)d_in[10];
    const float* Whr    = (const float*)d_in[11];
    const float* bhr    = (const float*)d_in[12];
    const float* Wch    = (const float*)d_in[13];
    const float* bch    = (const float*)d_in[14];
    const float* Wr     = (const float*)d_in[15];
    const float* br     = (const float*)d_in[16];
    const float* Wnm    = (const float*)d_in[17];
    const float* bnm    = (const float*)d_in[18];
    const float* alpha  = (const float*)d_in[19];
    const float* Wv     = (const float*)d_in[20];
    const float* bv     = (const float*)d_in[21];

    float* ws    = (float*)d_ws;
    float* x0    = ws;                   // 65536
    float* x1    = ws + 65536;           // 65536
    float* x2    = ws + 131072;          // 65536
    float* parts = ws + 196608;          // 64*64 = 4096
    int*   syncb = (int*)(ws + 200704);  // cnt_p[64], cnt_h[64], flag_nm[64]
    int*   cnt_p   = syncb;
    int*   cnt_h   = syncb + 64;
    int*   flag_nm = syncb + 128;

    float* out        = (float*)d_out;
    float* out_choice = out;                        // 64
    float* out_nm     = out + 64;                   // 64
    float* out_value  = out + 128;                  // 64
    float* out_newpw  = out + 192;                  // 67,108,864
    float* out_hidden = out + 192 + BB * HD * HD;   // 65,536

    k_gemm<II><<<512, 1024, 0, stream>>>(items, We, be, x0, syncb);
    k_gemm<HD><<<512, 1024, 0, stream>>>(x0, W1, b1, x1, nullptr);
    k_gemm<HD><<<512, 1024, 0, stream>>>(x1, W2, b2, x2, nullptr);
    k_fused<<<1024, 512, 0, stream>>>(pw, alpha, Wfc2, bfc2, x2, reward, Wr, br,
                                      Whr, bhr, Wnm, bnm, Wch, bch, Wv, bv,
                                      out_choice, out_nm, out_value, out_newpw,
                                      out_hidden, parts, cnt_p, cnt_h, flag_nm);
}

// Round 8
// 252.286 us; speedup vs baseline: 3.3004x; 3.3004x over previous
//
#include <hip/hip_runtime.h>

#define HD 1024
#define BB 64
#define II 512

typedef float f4 __attribute__((ext_vector_type(4)));

__device__ __forceinline__ float fast_tanh(float x) {
    float ax = __builtin_fabsf(x);
    float e  = __builtin_amdgcn_exp2f(ax * -2.8853900817779268f);  // exp(-2|x|)
    float t  = (1.0f - e) * __builtin_amdgcn_rcpf(1.0f + e);
    return x < 0.0f ? -t : t;
}

// out[b][h] = act( sum_k A[b][k] * W[h][k] + bias[h] ), act = tanh or identity
// Block = 1024 thr = 16 waves = 16 b's sharing one h-octet staged in LDS.
// grid 512 = 128 octets x 4 b-groups. First gemm zeroes sync counters.
template <int K, bool TANH>
__global__ __launch_bounds__(1024) void k_gemm(const float* __restrict__ A,    // [64][K]
                                               const float* __restrict__ W,    // [1024][K]
                                               const float* __restrict__ bias, // [1024]
                                               float* __restrict__ out,        // [64][1024]
                                               int* __restrict__ syncb)
{
    constexpr int J = K / 256;
    __shared__ float wlds[8 * K];

    int tid  = threadIdx.x;
    if (syncb && blockIdx.x == 0 && tid < 192) syncb[tid] = 0;

    int oct  = blockIdx.x & 127;
    int bg   = blockIdx.x >> 7;          // 0..3
    int h0   = oct * 8;

    {
        const f4* src = (const f4*)(W + (size_t)h0 * K);
        f4* dst = (f4*)wlds;
#pragma unroll
        for (int v = tid; v < 2 * K; v += 1024) dst[v] = src[v];
    }
    __syncthreads();

    int lane = tid & 63;
    int wave = tid >> 6;
    int b    = bg * 16 + wave;

    f4 a[J];
#pragma unroll
    for (int j = 0; j < J; ++j)
        a[j] = *(const f4*)(A + (size_t)b * K + j * 256 + lane * 4);

    float acc[8];
#pragma unroll
    for (int hh = 0; hh < 8; ++hh) {
        const float* wrow = wlds + hh * K;
        float s = 0.f;
#pragma unroll
        for (int j = 0; j < J; ++j) {
            f4 w4 = *(const f4*)(wrow + j * 256 + lane * 4);
            s += a[j].x * w4.x + a[j].y * w4.y + a[j].z * w4.z + a[j].w * w4.w;
        }
        acc[hh] = s;
    }
#pragma unroll
    for (int hh = 0; hh < 8; ++hh)
#pragma unroll
        for (int off = 32; off; off >>= 1)
            acc[hh] += __shfl_xor(acc[hh], off, 64);
    if (lane == 0) {
        f4 o0, o1;
        if (TANH) {
            o0.x = fast_tanh(acc[0] + bias[h0 + 0]);
            o0.y = fast_tanh(acc[1] + bias[h0 + 1]);
            o0.z = fast_tanh(acc[2] + bias[h0 + 2]);
            o0.w = fast_tanh(acc[3] + bias[h0 + 3]);
            o1.x = fast_tanh(acc[4] + bias[h0 + 4]);
            o1.y = fast_tanh(acc[5] + bias[h0 + 5]);
            o1.z = fast_tanh(acc[6] + bias[h0 + 6]);
            o1.w = fast_tanh(acc[7] + bias[h0 + 7]);
        } else {
            o0.x = acc[0] + bias[h0 + 0];
            o0.y = acc[1] + bias[h0 + 1];
            o0.z = acc[2] + bias[h0 + 2];
            o0.w = acc[3] + bias[h0 + 3];
            o1.x = acc[4] + bias[h0 + 4];
            o1.y = acc[5] + bias[h0 + 5];
            o1.z = acc[6] + bias[h0 + 6];
            o1.w = acc[7] + bias[h0 + 7];
        }
        *(f4*)(out + (size_t)b * HD + h0)     = o0;
        *(f4*)(out + (size_t)b * HD + h0 + 4) = o1;
    }
}

// Persistent fused kernel: 256 blocks x 1024 thr (1 block/CU — tight L3 window).
// 4 blocks per b; block owns h-slice [sub*256, sub*256+256), 16 rows/wave.
// Phase 1: plastic (pw+alpha, 2-row batched) + precomputed innate -> pre/hidden.
// Phase 2: hrc rows + nm/choice/value partials; sub0 finalizes nm[b].
// Phase 3: update (pw re-read from L2/L3, 2-row batched), NT stores.
__global__ __launch_bounds__(1024, 4) void k_fused(
        const float* __restrict__ pw,
        const float* __restrict__ alpha,
        const float* __restrict__ innate,  // [64][1024] = x2@Wfc2.T + bfc2
        const float* __restrict__ x2,      // [64][1024]
        const float* __restrict__ reward,  // [64]
        const float* __restrict__ Wr,      // [1024]
        const float* __restrict__ br,      // [1024]
        const float* __restrict__ Whr,
        const float* __restrict__ bhr,
        const float* __restrict__ Wnm,
        const float* __restrict__ bnm,
        const float* __restrict__ Wch,
        const float* __restrict__ bch,
        const float* __restrict__ Wv,
        const float* __restrict__ bv,
        float* __restrict__ out_choice,
        float* __restrict__ out_nm,
        float* __restrict__ out_value,
        float* __restrict__ out_newpw,
        float* __restrict__ out_hidden,
        float* __restrict__ parts,         // [64][4][4]
        int*   __restrict__ cnt_p,         // [64]
        int*   __restrict__ cnt_h,         // [64]
        int*   __restrict__ flag_nm)       // [64]
{
    __shared__ float xs[HD];
    __shared__ float pre_s[256];
    __shared__ float hid_s[256];
    __shared__ float hplus[HD];
    __shared__ float wred[16][4];
    __shared__ float nm_lds;

    int tid   = threadIdx.x;
    int lane  = tid & 63;
    int wave  = tid >> 6;          // 0..15
    int b     = blockIdx.x >> 2;
    int sub   = blockIdx.x & 3;
    int hbase = sub << 8;

    if (tid < 256) ((f4*)xs)[tid] = ((const f4*)(x2 + ((size_t)b << 10)))[tid];
    __syncthreads();

    // ---- Phase 1: plastic for 256-h slice, 16 rows/wave, 2-row batches ----
#pragma unroll 1
    for (int rp = 0; rp < 8; ++rp) {
        int hl = (wave << 4) + (rp << 1);
        int h  = hbase + hl;
        const float* pr0 = pw + ((size_t)b << 20) + ((size_t)h << 10);
        const float* pr1 = pr0 + HD;
        const float* ar0 = alpha + ((size_t)h << 10);
        const float* ar1 = ar0 + HD;
        f4 p0[4], p1[4], a0[4], a1[4];
#pragma unroll
        for (int j = 0; j < 4; ++j) {
            int i = j * 256 + lane * 4;
            p0[j] = *(const f4*)(pr0 + i);
            p1[j] = *(const f4*)(pr1 + i);
            a0[j] = *(const f4*)(ar0 + i);
            a1[j] = *(const f4*)(ar1 + i);
        }
        float acc0 = 0.f, acc1 = 0.f;
#pragma unroll
        for (int j = 0; j < 4; ++j) {
            int i = j * 256 + lane * 4;
            f4 x4 = *(const f4*)(xs + i);
            acc0 += a0[j].x * p0[j].x * x4.x + a0[j].y * p0[j].y * x4.y +
                    a0[j].z * p0[j].z * x4.z + a0[j].w * p0[j].w * x4.w;
            acc1 += a1[j].x * p1[j].x * x4.x + a1[j].y * p1[j].y * x4.y +
                    a1[j].z * p1[j].z * x4.z + a1[j].w * p1[j].w * x4.w;
        }
#pragma unroll
        for (int off = 32; off; off >>= 1) {
            acc0 += __shfl_xor(acc0, off, 64);
            acc1 += __shfl_xor(acc1, off, 64);
        }
        if (lane == 0) {
            float pv0 = innate[(b << 10) + h]     + acc0;
            float pv1 = innate[(b << 10) + h + 1] + acc1;
            float hv0 = fast_tanh(pv0);
            float hv1 = fast_tanh(pv1);
            pre_s[hl]     = pv0;
            pre_s[hl + 1] = pv1;
            hid_s[hl]     = hv0;
            hid_s[hl + 1] = hv1;
            out_hidden[(b << 10) + h]     = hv0;
            out_hidden[(b << 10) + h + 1] = hv1;
        }
    }
    __syncthreads();
    if (tid == 0) {
        __threadfence();
        __hip_atomic_fetch_add(&cnt_p[b], 1, __ATOMIC_ACQ_REL, __HIP_MEMORY_SCOPE_AGENT);
        while (__hip_atomic_load(&cnt_p[b], __ATOMIC_ACQUIRE, __HIP_MEMORY_SCOPE_AGENT) < 4)
            __builtin_amdgcn_s_sleep(1);
    }
    __syncthreads();

    // ---- Phase 2: hrc rows for slice + partial dots ----
    float rwd = reward[b];
    if (tid < HD) hplus[tid] = out_hidden[(b << 10) + tid] + rwd * Wr[tid] + br[tid];
    __syncthreads();

    float nm0 = 0.f, nm1 = 0.f;
#pragma unroll 1
    for (int rp = 0; rp < 8; ++rp) {
        int h2 = hbase + (wave << 4) + (rp << 1);
        const float* w0 = Whr + ((size_t)h2 << 10);
        const float* w1 = w0 + HD;
        f4 wa[4], wb_[4];
#pragma unroll
        for (int j = 0; j < 4; ++j) {
            int i = j * 256 + lane * 4;
            wa[j]  = *(const f4*)(w0 + i);
            wb_[j] = *(const f4*)(w1 + i);
        }
        float s0 = 0.f, s1 = 0.f;
#pragma unroll
        for (int j = 0; j < 4; ++j) {
            int i = j * 256 + lane * 4;
            f4 h4 = *(const f4*)(hplus + i);
            s0 += wa[j].x * h4.x + wa[j].y * h4.y + wa[j].z * h4.z + wa[j].w * h4.w;
            s1 += wb_[j].x * h4.x + wb_[j].y * h4.y + wb_[j].z * h4.z + wb_[j].w * h4.w;
        }
#pragma unroll
        for (int off = 32; off; off >>= 1) {
            s0 += __shfl_xor(s0, off, 64);
            s1 += __shfl_xor(s1, off, 64);
        }
        float hr0 = fast_tanh(s0 + bhr[h2]);
        float hr1 = fast_tanh(s1 + bhr[h2 + 1]);
        if (lane == 0) {
            nm0 += Wnm[h2] * hr0 + Wnm[h2 + 1] * hr1;
            nm1 += Wnm[HD + h2] * hr0 + Wnm[HD + h2 + 1] * hr1;
        }
    }
    float cv = 0.f, vv = 0.f;
    if (wave < 4) {
        int idx = (wave << 6) + lane;       // 0..255
        cv = Wch[hbase + idx] * hid_s[idx];
        vv = Wv[hbase + idx] * hid_s[idx];
#pragma unroll
        for (int off = 32; off; off >>= 1) {
            cv += __shfl_xor(cv, off, 64);
            vv += __shfl_xor(vv, off, 64);
        }
    }
    if (lane == 0) {
        wred[wave][0] = nm0; wred[wave][1] = nm1;
        wred[wave][2] = cv;  wred[wave][3] = vv;    // waves>=4 contribute 0 to cv/vv
    }
    __syncthreads();
    if (tid == 0) {
        float p0 = 0.f, p1 = 0.f, p2 = 0.f, p3 = 0.f;
        for (int w = 0; w < 16; ++w) {
            p0 += wred[w][0]; p1 += wred[w][1];
            p2 += wred[w][2]; p3 += wred[w][3];
        }
        float* pb = parts + b * 16 + sub * 4;
        pb[0] = p0; pb[1] = p1; pb[2] = p2; pb[3] = p3;
        __threadfence();
        __hip_atomic_fetch_add(&cnt_h[b], 1, __ATOMIC_ACQ_REL, __HIP_MEMORY_SCOPE_AGENT);
        if (sub == 0) {
            while (__hip_atomic_load(&cnt_h[b], __ATOMIC_ACQUIRE, __HIP_MEMORY_SCOPE_AGENT) < 4)
                __builtin_amdgcn_s_sleep(1);
            __threadfence();
            float s0 = 0.f, s1 = 0.f, s2 = 0.f, s3 = 0.f;
            for (int q = 0; q < 4; ++q) {          // fixed order -> deterministic
                const float* pp = parts + b * 16 + q * 4;
                s0 += pp[0]; s1 += pp[1]; s2 += pp[2]; s3 += pp[3];
            }
            float n0 = fast_tanh(s0 + bnm[0]);
            float n1 = fast_tanh(s1 + bnm[1]);
            float nv = n0 - n1;
            out_nm[b] = nv;
            float z = s2 + bch[0];
            out_choice[b] = __builtin_amdgcn_rcpf(1.0f + __builtin_amdgcn_exp2f(-z * 1.4426950408889634f));
            out_value[b]  = s3 + bv[0];
            __threadfence();
            __hip_atomic_store(&flag_nm[b], 1, __ATOMIC_RELEASE, __HIP_MEMORY_SCOPE_AGENT);
        }
        while (__hip_atomic_load(&flag_nm[b], __ATOMIC_ACQUIRE, __HIP_MEMORY_SCOPE_AGENT) == 0)
            __builtin_amdgcn_s_sleep(1);
        nm_lds = out_nm[b];
    }
    __syncthreads();
    float nb = nm_lds;

    // ---- Phase 3: update for the same h-slice (pw from L2/L3), 2-row batches ----
#pragma unroll 1
    for (int rp = 0; rp < 8; ++rp) {
        int hl = (wave << 4) + (rp << 1);
        int h  = hbase + hl;
        float ps0 = pre_s[hl];
        float ps1 = pre_s[hl + 1];
        size_t base0 = ((size_t)b << 20) + ((size_t)h << 10);
        f4 p0[4], p1[4];
#pragma unroll
        for (int j = 0; j < 4; ++j) {
            int i = j * 256 + lane * 4;
            p0[j] = *(const f4*)(pw + base0 + i);
            p1[j] = *(const f4*)(pw + base0 + HD + i);
        }
#pragma unroll
        for (int j = 0; j < 4; ++j) {
            int i = j * 256 + lane * 4;
            f4 x4 = *(const f4*)(xs + i);
            f4 o0, o1;
            o0.x = fminf(fmaxf(p0[j].x + nb * fast_tanh(ps0 * x4.x), -50.f), 50.f);
            o0.y = fminf(fmaxf(p0[j].y + nb * fast_tanh(ps0 * x4.y), -50.f), 50.f);
            o0.z = fminf(fmaxf(p0[j].z + nb * fast_tanh(ps0 * x4.z), -50.f), 50.f);
            o0.w = fminf(fmaxf(p0[j].w + nb * fast_tanh(ps0 * x4.w), -50.f), 50.f);
            o1.x = fminf(fmaxf(p1[j].x + nb * fast_tanh(ps1 * x4.x), -50.f), 50.f);
            o1.y = fminf(fmaxf(p1[j].y + nb * fast_tanh(ps1 * x4.y), -50.f), 50.f);
            o1.z = fminf(fmaxf(p1[j].z + nb * fast_tanh(ps1 * x4.z), -50.f), 50.f);
            o1.w = fminf(fmaxf(p1[j].w + nb * fast_tanh(ps1 * x4.w), -50.f), 50.f);
            __builtin_nontemporal_store(o0, (f4*)(out_newpw + base0 + i));
            __builtin_nontemporal_store(o1, (f4*)(out_newpw + base0 + HD + i));
        }
    }
}

extern "C" void kernel_launch(void* const* d_in, const int* in_sizes, int n_in,
                              void* d_out, int out_size, void* d_ws, size_t ws_size,
                              hipStream_t stream) {
    const float* items  = (const float*)d_in[0];
    const float* pw     = (const float*)d_in[1];
    const float* reward = (const float*)d_in[2];
    const float* We     = (const float*)d_in[3];
    const float* be     = (const float*)d_in[4];
    const float* W1     = (const float*)d_in[5];
    const float* b1     = (const float*)d_in[6];
    const float* W2     = (const float*)d_in[7];
    const float* b2     = (const float*)d_in[8];
    const float* Wfc2   = (const float*)d_in[9];
    const float* bfc2   = (const float*)d_in[10];
    const float* Whr    = (const float*)d_in[11];
    const float* bhr    = (const float*)d_in[12];
    const float* Wch    = (const float*)d_in[13];
    const float* bch    = (const float*)d_in[14];
    const float* Wr     = (const float*)d_in[15];
    const float* br     = (const float*)d_in[16];
    const float* Wnm    = (const float*)d_in[17];
    const float* bnm    = (const float*)d_in[18];
    const float* alpha  = (const float*)d_in[19];
    const float* Wv     = (const float*)d_in[20];
    const float* bv     = (const float*)d_in[21];

    float* ws     = (float*)d_ws;
    float* x0     = ws;                   // 65536
    float* x1     = ws + 65536;           // 65536
    float* x2     = ws + 131072;          // 65536
    float* innate = ws + 196608;          // 65536
    float* parts  = ws + 262144;          // 1024
    int*   syncb  = (int*)(ws + 263168);  // cnt_p[64], cnt_h[64], flag_nm[64]
    int*   cnt_p   = syncb;
    int*   cnt_h   = syncb + 64;
    int*   flag_nm = syncb + 128;

    float* out        = (float*)d_out;
    float* out_choice = out;                        // 64
    float* out_nm     = out + 64;                   // 64
    float* out_value  = out + 128;                  // 64
    float* out_newpw  = out + 192;                  // 67,108,864
    float* out_hidden = out + 192 + BB * HD * HD;   // 65,536

    k_gemm<II, true ><<<512, 1024, 0, stream>>>(items, We, be, x0, syncb);
    k_gemm<HD, true ><<<512, 1024, 0, stream>>>(x0, W1, b1, x1, nullptr);
    k_gemm<HD, true ><<<512, 1024, 0, stream>>>(x1, W2, b2, x2, nullptr);
    k_gemm<HD, false><<<512, 1024, 0, stream>>>(x2, Wfc2, bfc2, innate, nullptr);
    k_fused<<<256, 1024, 0, stream>>>(pw, alpha, innate, x2, reward, Wr, br,
                                      Whr, bhr, Wnm, bnm, Wch, bch, Wv, bv,
                                      out_choice, out_nm, out_value, out_newpw,
                                      out_hidden, parts, cnt_p, cnt_h, flag_nm);
}

// Round 9
// 217.169 us; speedup vs baseline: 3.8341x; 1.1617x over previous
//
#include <hip/hip_runtime.h>

#define HD 1024
#define BB 64
#define II 512
#define CPAD 32   // ints per counter (128 B) — one cache line each

typedef float f4 __attribute__((ext_vector_type(4)));

__device__ __forceinline__ float fast_tanh(float x) {
    float ax = __builtin_fabsf(x);
    float e  = __builtin_amdgcn_exp2f(ax * -2.8853900817779268f);  // exp(-2|x|)
    float t  = (1.0f - e) * __builtin_amdgcn_rcpf(1.0f + e);
    return x < 0.0f ? -t : t;
}

// out[b][h] = act( sum_k A[b][k] * W[h][k] + bias[h] ), act = tanh or identity
// Block = 1024 thr = 16 waves = 16 b's sharing one h-octet staged in LDS.
// grid 512 = 128 octets x 4 b-groups. First gemm zeroes sync counters.
template <int K, bool TANH>
__global__ __launch_bounds__(1024) void k_gemm(const float* __restrict__ A,    // [64][K]
                                               const float* __restrict__ W,    // [1024][K]
                                               const float* __restrict__ bias, // [1024]
                                               float* __restrict__ out,        // [64][1024]
                                               int* __restrict__ syncb)
{
    constexpr int J = K / 256;
    __shared__ float wlds[8 * K];

    int tid  = threadIdx.x;
    if (syncb && blockIdx.x == 0) {
        for (int v = tid; v < 3 * 64 * CPAD; v += 1024) syncb[v] = 0;
    }

    int oct  = blockIdx.x & 127;
    int bg   = blockIdx.x >> 7;          // 0..3
    int h0   = oct * 8;

    {
        const f4* src = (const f4*)(W + (size_t)h0 * K);
        f4* dst = (f4*)wlds;
#pragma unroll
        for (int v = tid; v < 2 * K; v += 1024) dst[v] = src[v];
    }
    __syncthreads();

    int lane = tid & 63;
    int wave = tid >> 6;
    int b    = bg * 16 + wave;

    f4 a[J];
#pragma unroll
    for (int j = 0; j < J; ++j)
        a[j] = *(const f4*)(A + (size_t)b * K + j * 256 + lane * 4);

    float acc[8];
#pragma unroll
    for (int hh = 0; hh < 8; ++hh) {
        const float* wrow = wlds + hh * K;
        float s = 0.f;
#pragma unroll
        for (int j = 0; j < J; ++j) {
            f4 w4 = *(const f4*)(wrow + j * 256 + lane * 4);
            s += a[j].x * w4.x + a[j].y * w4.y + a[j].z * w4.z + a[j].w * w4.w;
        }
        acc[hh] = s;
    }
#pragma unroll
    for (int hh = 0; hh < 8; ++hh)
#pragma unroll
        for (int off = 32; off; off >>= 1)
            acc[hh] += __shfl_xor(acc[hh], off, 64);
    if (lane == 0) {
        f4 o0, o1;
        if (TANH) {
            o0.x = fast_tanh(acc[0] + bias[h0 + 0]);
            o0.y = fast_tanh(acc[1] + bias[h0 + 1]);
            o0.z = fast_tanh(acc[2] + bias[h0 + 2]);
            o0.w = fast_tanh(acc[3] + bias[h0 + 3]);
            o1.x = fast_tanh(acc[4] + bias[h0 + 4]);
            o1.y = fast_tanh(acc[5] + bias[h0 + 5]);
            o1.z = fast_tanh(acc[6] + bias[h0 + 6]);
            o1.w = fast_tanh(acc[7] + bias[h0 + 7]);
        } else {
            o0.x = acc[0] + bias[h0 + 0];
            o0.y = acc[1] + bias[h0 + 1];
            o0.z = acc[2] + bias[h0 + 2];
            o0.w = acc[3] + bias[h0 + 3];
            o1.x = acc[4] + bias[h0 + 4];
            o1.y = acc[5] + bias[h0 + 5];
            o1.z = acc[6] + bias[h0 + 6];
            o1.w = acc[7] + bias[h0 + 7];
        }
        *(f4*)(out + (size_t)b * HD + h0)     = o0;
        *(f4*)(out + (size_t)b * HD + h0 + 4) = o1;
    }
}

// Persistent fused kernel: 256 blocks x 1024 thr (1 block/CU — tight L3 window).
// 4 blocks per b; block owns h-slice [sub*256, sub*256+256), 16 rows/wave.
// Sync protocol: RELEASE RMW on arrival (one writeback), RELAXED polling
// (no per-poll cache invalidate!), then exactly ONE ACQUIRE load.
__global__ __launch_bounds__(1024, 4) void k_fused(
        const float* __restrict__ pw,
        const float* __restrict__ alpha,
        const float* __restrict__ innate,  // [64][1024] = x2@Wfc2.T + bfc2
        const float* __restrict__ x2,      // [64][1024]
        const float* __restrict__ reward,  // [64]
        const float* __restrict__ Wr,      // [1024]
        const float* __restrict__ br,      // [1024]
        const float* __restrict__ Whr,
        const float* __restrict__ bhr,
        const float* __restrict__ Wnm,
        const float* __restrict__ bnm,
        const float* __restrict__ Wch,
        const float* __restrict__ bch,
        const float* __restrict__ Wv,
        const float* __restrict__ bv,
        float* __restrict__ out_choice,
        float* __restrict__ out_nm,
        float* __restrict__ out_value,
        float* __restrict__ out_newpw,
        float* __restrict__ out_hidden,
        float* __restrict__ parts,         // [64][4][4]
        int*   __restrict__ cnt_p,         // [64*CPAD]
        int*   __restrict__ cnt_h,         // [64*CPAD]
        int*   __restrict__ flag_nm)       // [64*CPAD]
{
    __shared__ float xs[HD];
    __shared__ float pre_s[256];
    __shared__ float hid_s[256];
    __shared__ float hplus[HD];
    __shared__ float wred[16][4];
    __shared__ float nm_lds;

    int tid   = threadIdx.x;
    int lane  = tid & 63;
    int wave  = tid >> 6;          // 0..15
    int b     = blockIdx.x >> 2;
    int sub   = blockIdx.x & 3;
    int hbase = sub << 8;

    if (tid < 256) ((f4*)xs)[tid] = ((const f4*)(x2 + ((size_t)b << 10)))[tid];
    __syncthreads();

    // ---- Phase 1: plastic for 256-h slice, 16 rows/wave, 2-row batches ----
#pragma unroll 1
    for (int rp = 0; rp < 8; ++rp) {
        int hl = (wave << 4) + (rp << 1);
        int h  = hbase + hl;
        const float* pr0 = pw + ((size_t)b << 20) + ((size_t)h << 10);
        const float* pr1 = pr0 + HD;
        const float* ar0 = alpha + ((size_t)h << 10);
        const float* ar1 = ar0 + HD;
        f4 p0[4], p1[4], a0[4], a1[4];
#pragma unroll
        for (int j = 0; j < 4; ++j) {
            int i = j * 256 + lane * 4;
            p0[j] = *(const f4*)(pr0 + i);
            p1[j] = *(const f4*)(pr1 + i);
            a0[j] = *(const f4*)(ar0 + i);
            a1[j] = *(const f4*)(ar1 + i);
        }
        float acc0 = 0.f, acc1 = 0.f;
#pragma unroll
        for (int j = 0; j < 4; ++j) {
            int i = j * 256 + lane * 4;
            f4 x4 = *(const f4*)(xs + i);
            acc0 += a0[j].x * p0[j].x * x4.x + a0[j].y * p0[j].y * x4.y +
                    a0[j].z * p0[j].z * x4.z + a0[j].w * p0[j].w * x4.w;
            acc1 += a1[j].x * p1[j].x * x4.x + a1[j].y * p1[j].y * x4.y +
                    a1[j].z * p1[j].z * x4.z + a1[j].w * p1[j].w * x4.w;
        }
#pragma unroll
        for (int off = 32; off; off >>= 1) {
            acc0 += __shfl_xor(acc0, off, 64);
            acc1 += __shfl_xor(acc1, off, 64);
        }
        if (lane == 0) {
            float pv0 = innate[(b << 10) + h]     + acc0;
            float pv1 = innate[(b << 10) + h + 1] + acc1;
            float hv0 = fast_tanh(pv0);
            float hv1 = fast_tanh(pv1);
            pre_s[hl]     = pv0;
            pre_s[hl + 1] = pv1;
            hid_s[hl]     = hv0;
            hid_s[hl + 1] = hv1;
            out_hidden[(b << 10) + h]     = hv0;
            out_hidden[(b << 10) + h + 1] = hv1;
        }
    }
    __syncthreads();
    if (tid == 0) {
        // RELEASE arrival (writes back out_hidden), RELAXED poll, ONE acquire.
        __hip_atomic_fetch_add(&cnt_p[b * CPAD], 1, __ATOMIC_RELEASE, __HIP_MEMORY_SCOPE_AGENT);
        while (__hip_atomic_load(&cnt_p[b * CPAD], __ATOMIC_RELAXED, __HIP_MEMORY_SCOPE_AGENT) < 4)
            __builtin_amdgcn_s_sleep(1);
        (void)__hip_atomic_load(&cnt_p[b * CPAD], __ATOMIC_ACQUIRE, __HIP_MEMORY_SCOPE_AGENT);
    }
    __syncthreads();

    // ---- Phase 2: hrc rows for slice + partial dots ----
    float rwd = reward[b];
    if (tid < HD) hplus[tid] = out_hidden[(b << 10) + tid] + rwd * Wr[tid] + br[tid];
    __syncthreads();

    float nm0 = 0.f, nm1 = 0.f;
#pragma unroll 1
    for (int rp = 0; rp < 8; ++rp) {
        int h2 = hbase + (wave << 4) + (rp << 1);
        const float* w0 = Whr + ((size_t)h2 << 10);
        const float* w1 = w0 + HD;
        f4 wa[4], wb_[4];
#pragma unroll
        for (int j = 0; j < 4; ++j) {
            int i = j * 256 + lane * 4;
            wa[j]  = *(const f4*)(w0 + i);
            wb_[j] = *(const f4*)(w1 + i);
        }
        float s0 = 0.f, s1 = 0.f;
#pragma unroll
        for (int j = 0; j < 4; ++j) {
            int i = j * 256 + lane * 4;
            f4 h4 = *(const f4*)(hplus + i);
            s0 += wa[j].x * h4.x + wa[j].y * h4.y + wa[j].z * h4.z + wa[j].w * h4.w;
            s1 += wb_[j].x * h4.x + wb_[j].y * h4.y + wb_[j].z * h4.z + wb_[j].w * h4.w;
        }
#pragma unroll
        for (int off = 32; off; off >>= 1) {
            s0 += __shfl_xor(s0, off, 64);
            s1 += __shfl_xor(s1, off, 64);
        }
        float hr0 = fast_tanh(s0 + bhr[h2]);
        float hr1 = fast_tanh(s1 + bhr[h2 + 1]);
        if (lane == 0) {
            nm0 += Wnm[h2] * hr0 + Wnm[h2 + 1] * hr1;
            nm1 += Wnm[HD + h2] * hr0 + Wnm[HD + h2 + 1] * hr1;
        }
    }
    float cv = 0.f, vv = 0.f;
    if (wave < 4) {
        int idx = (wave << 6) + lane;       // 0..255
        cv = Wch[hbase + idx] * hid_s[idx];
        vv = Wv[hbase + idx] * hid_s[idx];
#pragma unroll
        for (int off = 32; off; off >>= 1) {
            cv += __shfl_xor(cv, off, 64);
            vv += __shfl_xor(vv, off, 64);
        }
    }
    if (lane == 0) {
        wred[wave][0] = nm0; wred[wave][1] = nm1;
        wred[wave][2] = cv;  wred[wave][3] = vv;    // waves>=4 contribute 0 to cv/vv
    }
    __syncthreads();
    if (tid == 0) {
        float p0 = 0.f, p1 = 0.f, p2 = 0.f, p3 = 0.f;
        for (int w = 0; w < 16; ++w) {
            p0 += wred[w][0]; p1 += wred[w][1];
            p2 += wred[w][2]; p3 += wred[w][3];
        }
        float* pb = parts + b * 16 + sub * 4;
        pb[0] = p0; pb[1] = p1; pb[2] = p2; pb[3] = p3;
        __hip_atomic_fetch_add(&cnt_h[b * CPAD], 1, __ATOMIC_RELEASE, __HIP_MEMORY_SCOPE_AGENT);
        if (sub == 0) {
            while (__hip_atomic_load(&cnt_h[b * CPAD], __ATOMIC_RELAXED, __HIP_MEMORY_SCOPE_AGENT) < 4)
                __builtin_amdgcn_s_sleep(1);
            (void)__hip_atomic_load(&cnt_h[b * CPAD], __ATOMIC_ACQUIRE, __HIP_MEMORY_SCOPE_AGENT);
            float s0 = 0.f, s1 = 0.f, s2 = 0.f, s3 = 0.f;
            for (int q = 0; q < 4; ++q) {          // fixed order -> deterministic
                const float* pp = parts + b * 16 + q * 4;
                s0 += pp[0]; s1 += pp[1]; s2 += pp[2]; s3 += pp[3];
            }
            float n0 = fast_tanh(s0 + bnm[0]);
            float n1 = fast_tanh(s1 + bnm[1]);
            float nv = n0 - n1;
            out_nm[b] = nv;
            float z = s2 + bch[0];
            out_choice[b] = __builtin_amdgcn_rcpf(1.0f + __builtin_amdgcn_exp2f(-z * 1.4426950408889634f));
            out_value[b]  = s3 + bv[0];
            __hip_atomic_store(&flag_nm[b * CPAD], 1, __ATOMIC_RELEASE, __HIP_MEMORY_SCOPE_AGENT);
        }
        while (__hip_atomic_load(&flag_nm[b * CPAD], __ATOMIC_RELAXED, __HIP_MEMORY_SCOPE_AGENT) == 0)
            __builtin_amdgcn_s_sleep(1);
        (void)__hip_atomic_load(&flag_nm[b * CPAD], __ATOMIC_ACQUIRE, __HIP_MEMORY_SCOPE_AGENT);
        nm_lds = out_nm[b];
    }
    __syncthreads();
    float nb = nm_lds;

    // ---- Phase 3: update for the same h-slice (pw from L2/L3), 2-row batches ----
#pragma unroll 1
    for (int rp = 0; rp < 8; ++rp) {
        int hl = (wave << 4) + (rp << 1);
        int h  = hbase + hl;
        float ps0 = pre_s[hl];
        float ps1 = pre_s[hl + 1];
        size_t base0 = ((size_t)b << 20) + ((size_t)h << 10);
        f4 p0[4], p1[4];
#pragma unroll
        for (int j = 0; j < 4; ++j) {
            int i = j * 256 + lane * 4;
            p0[j] = *(const f4*)(pw + base0 + i);
            p1[j] = *(const f4*)(pw + base0 + HD + i);
        }
#pragma unroll
        for (int j = 0; j < 4; ++j) {
            int i = j * 256 + lane * 4;
            f4 x4 = *(const f4*)(xs + i);
            f4 o0, o1;
            o0.x = fminf(fmaxf(p0[j].x + nb * fast_tanh(ps0 * x4.x), -50.f), 50.f);
            o0.y = fminf(fmaxf(p0[j].y + nb * fast_tanh(ps0 * x4.y), -50.f), 50.f);
            o0.z = fminf(fmaxf(p0[j].z + nb * fast_tanh(ps0 * x4.z), -50.f), 50.f);
            o0.w = fminf(fmaxf(p0[j].w + nb * fast_tanh(ps0 * x4.w), -50.f), 50.f);
            o1.x = fminf(fmaxf(p1[j].x + nb * fast_tanh(ps1 * x4.x), -50.f), 50.f);
            o1.y = fminf(fmaxf(p1[j].y + nb * fast_tanh(ps1 * x4.y), -50.f), 50.f);
            o1.z = fminf(fmaxf(p1[j].z + nb * fast_tanh(ps1 * x4.z), -50.f), 50.f);
            o1.w = fminf(fmaxf(p1[j].w + nb * fast_tanh(ps1 * x4.w), -50.f), 50.f);
            __builtin_nontemporal_store(o0, (f4*)(out_newpw + base0 + i));
            __builtin_nontemporal_store(o1, (f4*)(out_newpw + base0 + HD + i));
        }
    }
}

extern "C" void kernel_launch(void* const* d_in, const int* in_sizes, int n_in,
                              void* d_out, int out_size, void* d_ws, size_t ws_size,
                              hipStream_t stream) {
    const float* items  = (const float*)d_in[0];
    const float* pw     = (const float*)d_in[1];
    const float* reward = (const float*)d_in[2];
    const float* We     = (const float*)d_in[3];
    const float* be     = (const float*)d_in[4];
    const float* W1     = (const float*)d_in[5];
    const float* b1     = (const float*)d_in[6];
    const float* W2     = (const float*)d_in[7];
    const float* b2     = (const float*)d_in[8];
    const float* Wfc2   = (const float*)d_in[9];
    const float* bfc2   = (const float*)d_in[10];
    const float* Whr    = (const float*)d_in[11];
    const float* bhr    = (const float*)d_in[12];
    const float* Wch    = (const float*)d_in[13];
    const float* bch    = (const float*)d_in[14];
    const float* Wr     = (const float*)d_in[15];
    const float* br     = (const float*)d_in[16];
    const float* Wnm    = (const float*)d_in[17];
    const float* bnm    = (const float*)d_in[18];
    const float* alpha  = (const float*)d_in[19];
    const float* Wv     = (const float*)d_in[20];
    const float* bv     = (const float*)d_in[21];

    float* ws     = (float*)d_ws;
    float* x0     = ws;                   // 65536
    float* x1     = ws + 65536;           // 65536
    float* x2     = ws + 131072;          // 65536
    float* innate = ws + 196608;          // 65536
    float* parts  = ws + 262144;          // 1024
    int*   syncb  = (int*)(ws + 263168);  // 3 * 64 * CPAD ints
    int*   cnt_p   = syncb;
    int*   cnt_h   = syncb + 64 * CPAD;
    int*   flag_nm = syncb + 128 * CPAD;

    float* out        = (float*)d_out;
    float* out_choice = out;                        // 64
    float* out_nm     = out + 64;                   // 64
    float* out_value  = out + 128;                  // 64
    float* out_newpw  = out + 192;                  // 67,108,864
    float* out_hidden = out + 192 + BB * HD * HD;   // 65,536

    k_gemm<II, true ><<<512, 1024, 0, stream>>>(items, We, be, x0, syncb);
    k_gemm<HD, true ><<<512, 1024, 0, stream>>>(x0, W1, b1, x1, nullptr);
    k_gemm<HD, true ><<<512, 1024, 0, stream>>>(x1, W2, b2, x2, nullptr);
    k_gemm<HD, false><<<512, 1024, 0, stream>>>(x2, Wfc2, bfc2, innate, nullptr);
    k_fused<<<256, 1024, 0, stream>>>(pw, alpha, innate, x2, reward, Wr, br,
                                      Whr, bhr, Wnm, bnm, Wch, bch, Wv, bv,
                                      out_choice, out_nm, out_value, out_newpw,
                                      out_hidden, parts, cnt_p, cnt_h, flag_nm);
}